// Round 3
// baseline (318.919 us; speedup 1.0000x reference)
//
#include <hip/hip_runtime.h>
#include <hip/hip_cooperative_groups.h>
#include <math.h>

// SpectralConv1d: y = irfft( einsum('bim,iom->bom', rfft(x)[:,:,:16], W) )
// B=64, Cin=64, Cout=64, MODES=16, RES=8192.
// Single cooperative kernel: phase A (16-mode DFT per input row) ->
// grid.sync() -> phase C (Cin contraction + 16-mode synthesis per output row).
// n = a + 512*b factorization; inner 16-pt real DFT with constant twiddles
// (even/odd folded); outer 512-term sum via rotation recurrence.
// ws: X [4096][32] f32 = 512 KB.

#define B_     64
#define CIN_   64
#define COUT_  64
#define MODES_ 16
#define RES_   8192
#define NA     512          // RES_/16
#define PITCH  514          // LDS row pitch for Ts (even; 2*PITCH%32==4 -> <=2-way)
#define NROW   4096

namespace cg = cooperative_groups;

__device__ static constexpr float COS16[16] = {
     1.0f,  0.92387953251128674f,  0.70710678118654752f,  0.38268343236508977f,
     0.0f, -0.38268343236508977f, -0.70710678118654752f, -0.92387953251128674f,
    -1.0f, -0.92387953251128674f, -0.70710678118654752f, -0.38268343236508977f,
     0.0f,  0.38268343236508977f,  0.70710678118654752f,  0.92387953251128674f
};
__device__ static constexpr float SIN16[16] = {
     0.0f,  0.38268343236508977f,  0.70710678118654752f,  0.92387953251128674f,
     1.0f,  0.92387953251128674f,  0.70710678118654752f,  0.38268343236508977f,
     0.0f, -0.38268343236508977f, -0.70710678118654752f, -0.92387953251128674f,
    -1.0f, -0.92387953251128674f, -0.70710678118654752f, -0.38268343236508977f
};

#define W8192 7.66990393942820428e-4f   // 2*pi/8192

struct SharedA {
    float Ts[18 * PITCH];   // [kslot][a]: kslot=2k(re),2k+1(im), k=0..8  (~37 KB)
    float P[16][17][2];
};
struct SharedC {
    float Xs[CIN_ * 32];    // 8 KB
    float Ps[16][17][2];
    float Csh[32];
};
union SharedU { SharedA a; SharedC c; };

__global__ __launch_bounds__(256, 4) void fused(const float* __restrict__ x,
                                                const float* __restrict__ wr,
                                                const float* __restrict__ wi,
                                                float* __restrict__ X,
                                                float* __restrict__ y) {
    cg::grid_group grid = cg::this_grid();
    __shared__ SharedU sh;
    const int tid = threadIdx.x;
    const int R  = (NROW + gridDim.x - 1) / gridDim.x;
    const int r0 = blockIdx.x * R;
    const int r1 = (r0 + R < NROW) ? (r0 + R) : NROW;

    // ---------------- Phase A ----------------
    // hoisted per-tid twiddle bases (row-independent)
    const int k  = tid & 15;
    const int c  = tid >> 4;             // a-residue 0..15
    const int kp = (k <= 8) ? k : 16 - k;
    const float sgn = (k <= 8) ? 1.f : -1.f;
    float sA, cA, sB, cB;
    __sincosf((float)(k * c)  * W8192, &sA, &cA);
    __sincosf((float)(k * 16) * W8192, &sB, &cB);
    const float wre0 = cA, wim0 = -sA;   // e^{-2pi i k c/8192}
    const float sre = cB, sim = -sB;     // e^{-2pi i k*16/8192}

    for (int row = r0; row < r1; ++row) {
        const float* __restrict__ xr = x + (size_t)row * RES_;
        // 16-pt real DFT over b at a = 2*tid, 2*tid+1 (float2 loads)
        float2 m[16];
#pragma unroll
        for (int b = 0; b < 16; ++b)
            m[b] = *(const float2*)(xr + 2 * tid + NA * b);
        float2 x0 = m[0], x8 = m[8];
        float2 ev[8], ov[8];
#pragma unroll
        for (int b = 1; b <= 7; ++b) {
            ev[b].x = m[b].x + m[16 - b].x;  ev[b].y = m[b].y + m[16 - b].y;
            ov[b].x = m[b].x - m[16 - b].x;  ov[b].y = m[b].y - m[16 - b].y;
        }
#pragma unroll
        for (int kk = 0; kk <= 8; ++kk) {
            float sr0 = (kk & 1) ? (x0.x - x8.x) : (x0.x + x8.x);
            float sr1 = (kk & 1) ? (x0.y - x8.y) : (x0.y + x8.y);
            float si0 = 0.f, si1 = 0.f;
#pragma unroll
            for (int b = 1; b <= 7; ++b) {
                const float cc = COS16[(kk * b) & 15];
                const float ss = SIN16[(kk * b) & 15];
                sr0 = fmaf(ev[b].x, cc, sr0);
                sr1 = fmaf(ev[b].y, cc, sr1);
                si0 = fmaf(ov[b].x, -ss, si0);
                si1 = fmaf(ov[b].y, -ss, si1);
            }
            *(float2*)&sh.a.Ts[(2 * kk) * PITCH + 2 * tid]     = make_float2(sr0, sr1);
            *(float2*)&sh.a.Ts[(2 * kk + 1) * PITCH + 2 * tid] = make_float2(si0, si1);
        }
        __syncthreads();

        // outer 512-sum with rotation recurrence
        float wre = wre0, wim = wim0;
        float accr = 0.f, acci = 0.f;
        const float* __restrict__ Tr = &sh.a.Ts[(2 * kp) * PITCH + c];
        const float* __restrict__ Ti = &sh.a.Ts[(2 * kp + 1) * PITCH + c];
#pragma unroll 8
        for (int j = 0; j < 32; ++j) {
            const float tr = Tr[16 * j];
            const float ti = sgn * Ti[16 * j];
            accr = fmaf(wre, tr, fmaf(-wim, ti, accr));
            acci = fmaf(wre, ti, fmaf( wim, tr, acci));
            const float nre = fmaf(wre, sre, -wim * sim);
            wim = fmaf(wre, sim, wim * sre);
            wre = nre;
        }
        sh.a.P[k][c][0] = accr;
        sh.a.P[k][c][1] = acci;
        __syncthreads();
        if (tid < 16) {
            float xre = 0.f, xim = 0.f;
#pragma unroll
            for (int c2 = 0; c2 < 16; ++c2) { xre += sh.a.P[tid][c2][0]; xim += sh.a.P[tid][c2][1]; }
            *(float2*)&X[row * 32 + 2 * tid] = make_float2(xre, xim);
        }
        // no extra sync needed: next row's Ts writes are ordered after this
        // row's Ts reads by the phase-2 entry sync.
        __syncthreads();
    }

    grid.sync();

    // ---------------- Phase C ----------------
    // hoisted per-tid synthesis step twiddles
    float su0, cu0, su1, cu1;
    __sincosf((float)(2 * tid)     * W8192, &su0, &cu0);
    __sincosf((float)(2 * tid + 1) * W8192, &su1, &cu1);

    int curb = -1;
    for (int row = r0; row < r1; ++row) {
        const int b = row >> 6, o = row & 63;
        if (b != curb) {
            __syncthreads();
            const float4* __restrict__ Xb4 = (const float4*)(X + (size_t)b * CIN_ * 32);
            for (int t = tid; t < CIN_ * 8; t += 256)
                ((float4*)sh.c.Xs)[t] = Xb4[t];
            __syncthreads();
            curb = b;
        }

        // Cin contraction -> Csh
        {
            const int kk = tid & 15, p = tid >> 4;
            float pr = 0.f, pi = 0.f;
#pragma unroll
            for (int mI = 0; mI < 4; ++mI) {
                const int i = 4 * p + mI;
                const float xre = sh.c.Xs[i * 32 + 2 * kk];
                const float xim = sh.c.Xs[i * 32 + 2 * kk + 1];
                const float wrv = wr[(i * COUT_ + o) * MODES_ + kk];
                const float wiv = wi[(i * COUT_ + o) * MODES_ + kk];
                pr = fmaf(xre, wrv, fmaf(-xim, wiv, pr));
                pi = fmaf(xre, wiv, fmaf( xim, wrv, pi));
            }
            sh.c.Ps[kk][p][0] = pr;
            sh.c.Ps[kk][p][1] = pi;
        }
        __syncthreads();
        if (tid < 32) {
            const int kk = tid & 15, comp = tid >> 4;
            float s = 0.f;
#pragma unroll
            for (int p = 0; p < 16; ++p) s += sh.c.Ps[kk][p][comp];
            const float g = (kk == 0) ? (1.0f / RES_) : (2.0f / RES_);
            sh.c.Csh[2 * kk + comp] = g * s;
        }
        __syncthreads();

        float C[32];
#pragma unroll
        for (int q = 0; q < 8; ++q) {
            const float4 v = ((const float4*)sh.c.Csh)[q];
            C[4 * q] = v.x; C[4 * q + 1] = v.y; C[4 * q + 2] = v.z; C[4 * q + 3] = v.w;
        }

        float* __restrict__ yr = y + (size_t)row * RES_;
        float yv[16][2];
#pragma unroll
        for (int half = 0; half < 2; ++half) {
            const float su = half ? su1 : su0;
            const float cu = half ? cu1 : cu0;
            float wre = 1.f, wim = 0.f;
            float Er0 = 0.f, Er8 = 0.f, Er[8], Oi[8];
#pragma unroll
            for (int q = 1; q <= 7; ++q) { Er[q] = 0.f; Oi[q] = 0.f; }
#pragma unroll
            for (int kk = 0; kk < 16; ++kk) {
                const float cre = C[2 * kk], cim = C[2 * kk + 1];
                const float dre = fmaf(cre, wre, -cim * wim);
                const float dim = fmaf(cre, wim,  cim * wre);
                if (kk == 0)      { Er0 = dre; }
                else if (kk == 8) { Er8 = dre; }
                else if (kk < 8)  { Er[kk]      += dre; Oi[kk]      += dim; }
                else              { Er[16 - kk] += dre; Oi[16 - kk] -= dim; }
                const float nre = fmaf(wre, cu, -wim * su);
                wim = fmaf(wre, su, wim * cu);
                wre = nre;
            }
#pragma unroll
            for (int bb = 0; bb <= 8; ++bb) {
                float Cc = (bb & 1) ? (Er0 - Er8) : (Er0 + Er8);
                float Ss = 0.f;
#pragma unroll
                for (int q = 1; q <= 7; ++q) {
                    Cc = fmaf(Er[q], COS16[(q * bb) & 15], Cc);
                    Ss = fmaf(Oi[q], SIN16[(q * bb) & 15], Ss);
                }
                if (bb == 0)      yv[0][half] = Cc;
                else if (bb == 8) yv[8][half] = Cc;
                else { yv[bb][half] = Cc - Ss; yv[16 - bb][half] = Cc + Ss; }
            }
        }
#pragma unroll
        for (int bb = 0; bb < 16; ++bb)
            *(float2*)(yr + NA * bb + 2 * tid) = make_float2(yv[bb][0], yv[bb][1]);
        __syncthreads();
    }
}

// ---------------- fallback path (plain two-kernel), used only if the
// cooperative launch is rejected at runtime ----------------
__global__ __launch_bounds__(256) void kA(const float* __restrict__ x,
                                          float* __restrict__ X) {
    __shared__ SharedA sa;
    const int row = blockIdx.x;
    const int tid = threadIdx.x;
    const float* __restrict__ xr = x + (size_t)row * RES_;
    float2 m[16];
#pragma unroll
    for (int b = 0; b < 16; ++b) m[b] = *(const float2*)(xr + 2 * tid + NA * b);
    float2 x0 = m[0], x8 = m[8];
    float2 ev[8], ov[8];
#pragma unroll
    for (int b = 1; b <= 7; ++b) {
        ev[b].x = m[b].x + m[16 - b].x;  ev[b].y = m[b].y + m[16 - b].y;
        ov[b].x = m[b].x - m[16 - b].x;  ov[b].y = m[b].y - m[16 - b].y;
    }
#pragma unroll
    for (int kk = 0; kk <= 8; ++kk) {
        float sr0 = (kk & 1) ? (x0.x - x8.x) : (x0.x + x8.x);
        float sr1 = (kk & 1) ? (x0.y - x8.y) : (x0.y + x8.y);
        float si0 = 0.f, si1 = 0.f;
#pragma unroll
        for (int b = 1; b <= 7; ++b) {
            const float cc = COS16[(kk * b) & 15];
            const float ss = SIN16[(kk * b) & 15];
            sr0 = fmaf(ev[b].x, cc, sr0);
            sr1 = fmaf(ev[b].y, cc, sr1);
            si0 = fmaf(ov[b].x, -ss, si0);
            si1 = fmaf(ov[b].y, -ss, si1);
        }
        *(float2*)&sa.Ts[(2 * kk) * PITCH + 2 * tid]     = make_float2(sr0, sr1);
        *(float2*)&sa.Ts[(2 * kk + 1) * PITCH + 2 * tid] = make_float2(si0, si1);
    }
    __syncthreads();
    const int k = tid & 15, c = tid >> 4;
    const int kp = (k <= 8) ? k : 16 - k;
    const float sgn = (k <= 8) ? 1.f : -1.f;
    float sA, cA, sB, cB;
    __sincosf((float)(k * c)  * W8192, &sA, &cA);
    __sincosf((float)(k * 16) * W8192, &sB, &cB);
    float wre = cA, wim = -sA;
    const float sre = cB, sim = -sB;
    float accr = 0.f, acci = 0.f;
    const float* __restrict__ Tr = &sa.Ts[(2 * kp) * PITCH + c];
    const float* __restrict__ Ti = &sa.Ts[(2 * kp + 1) * PITCH + c];
#pragma unroll 8
    for (int j = 0; j < 32; ++j) {
        const float tr = Tr[16 * j];
        const float ti = sgn * Ti[16 * j];
        accr = fmaf(wre, tr, fmaf(-wim, ti, accr));
        acci = fmaf(wre, ti, fmaf( wim, tr, acci));
        const float nre = fmaf(wre, sre, -wim * sim);
        wim = fmaf(wre, sim, wim * sre);
        wre = nre;
    }
    sa.P[k][c][0] = accr;
    sa.P[k][c][1] = acci;
    __syncthreads();
    if (tid < 16) {
        float xre = 0.f, xim = 0.f;
#pragma unroll
        for (int c2 = 0; c2 < 16; ++c2) { xre += sa.P[tid][c2][0]; xim += sa.P[tid][c2][1]; }
        *(float2*)&X[row * 32 + 2 * tid] = make_float2(xre, xim);
    }
}

__global__ __launch_bounds__(256) void kC(const float* __restrict__ X,
                                          const float* __restrict__ wr,
                                          const float* __restrict__ wi,
                                          float* __restrict__ y) {
    __shared__ SharedC sc;
    const int row = blockIdx.x;
    const int b = row >> 6, o = row & 63;
    const int tid = threadIdx.x;
    const float4* __restrict__ Xb4 = (const float4*)(X + (size_t)b * CIN_ * 32);
    for (int t = tid; t < CIN_ * 8; t += 256) ((float4*)sc.Xs)[t] = Xb4[t];
    __syncthreads();
    {
        const int kk = tid & 15, p = tid >> 4;
        float pr = 0.f, pi = 0.f;
#pragma unroll
        for (int mI = 0; mI < 4; ++mI) {
            const int i = 4 * p + mI;
            const float xre = sc.Xs[i * 32 + 2 * kk];
            const float xim = sc.Xs[i * 32 + 2 * kk + 1];
            const float wrv = wr[(i * COUT_ + o) * MODES_ + kk];
            const float wiv = wi[(i * COUT_ + o) * MODES_ + kk];
            pr = fmaf(xre, wrv, fmaf(-xim, wiv, pr));
            pi = fmaf(xre, wiv, fmaf( xim, wrv, pi));
        }
        sc.Ps[kk][p][0] = pr;
        sc.Ps[kk][p][1] = pi;
    }
    __syncthreads();
    if (tid < 32) {
        const int kk = tid & 15, comp = tid >> 4;
        float s = 0.f;
#pragma unroll
        for (int p = 0; p < 16; ++p) s += sc.Ps[kk][p][comp];
        const float g = (kk == 0) ? (1.0f / RES_) : (2.0f / RES_);
        sc.Csh[2 * kk + comp] = g * s;
    }
    __syncthreads();
    float C[32];
#pragma unroll
    for (int q = 0; q < 8; ++q) {
        const float4 v = ((const float4*)sc.Csh)[q];
        C[4 * q] = v.x; C[4 * q + 1] = v.y; C[4 * q + 2] = v.z; C[4 * q + 3] = v.w;
    }
    float* __restrict__ yr = y + (size_t)row * RES_;
    float yv[16][2];
#pragma unroll
    for (int half = 0; half < 2; ++half) {
        const int a = 2 * tid + half;
        float su, cu;
        __sincosf((float)a * W8192, &su, &cu);
        float wre = 1.f, wim = 0.f;
        float Er0 = 0.f, Er8 = 0.f, Er[8], Oi[8];
#pragma unroll
        for (int q = 1; q <= 7; ++q) { Er[q] = 0.f; Oi[q] = 0.f; }
#pragma unroll
        for (int kk = 0; kk < 16; ++kk) {
            const float cre = C[2 * kk], cim = C[2 * kk + 1];
            const float dre = fmaf(cre, wre, -cim * wim);
            const float dim = fmaf(cre, wim,  cim * wre);
            if (kk == 0)      { Er0 = dre; }
            else if (kk == 8) { Er8 = dre; }
            else if (kk < 8)  { Er[kk]      += dre; Oi[kk]      += dim; }
            else              { Er[16 - kk] += dre; Oi[16 - kk] -= dim; }
            const float nre = fmaf(wre, cu, -wim * su);
            wim = fmaf(wre, su, wim * cu);
            wre = nre;
        }
#pragma unroll
        for (int bb = 0; bb <= 8; ++bb) {
            float Cc = (bb & 1) ? (Er0 - Er8) : (Er0 + Er8);
            float Ss = 0.f;
#pragma unroll
            for (int q = 1; q <= 7; ++q) {
                Cc = fmaf(Er[q], COS16[(q * bb) & 15], Cc);
                Ss = fmaf(Oi[q], SIN16[(q * bb) & 15], Ss);
            }
            if (bb == 0)      yv[0][half] = Cc;
            else if (bb == 8) yv[8][half] = Cc;
            else { yv[bb][half] = Cc - Ss; yv[16 - bb][half] = Cc + Ss; }
        }
    }
#pragma unroll
    for (int bb = 0; bb < 16; ++bb)
        *(float2*)(yr + NA * bb + 2 * tid) = make_float2(yv[bb][0], yv[bb][1]);
}

extern "C" void kernel_launch(void* const* d_in, const int* in_sizes, int n_in,
                              void* d_out, int out_size, void* d_ws, size_t ws_size,
                              hipStream_t stream) {
    const float* x  = (const float*)d_in[0];
    const float* wr = (const float*)d_in[1];
    const float* wi = (const float*)d_in[2];
    float* out = (float*)d_out;
    float* X = (float*)d_ws;             // [4096][32] = 512 KB

    int nb = 0;
    (void)hipOccupancyMaxActiveBlocksPerMultiprocessor(&nb, fused, 256, 0);
    if (nb < 1) nb = 1;
    int gridn = nb * 256;                // 256 CUs on MI355X
    if (gridn > 1024) gridn = 1024;

    void* args[] = {(void*)&x, (void*)&wr, (void*)&wi, (void*)&X, (void*)&out};
    hipError_t err = hipLaunchCooperativeKernel((const void*)fused, dim3(gridn),
                                                dim3(256), args, 0, stream);
    if (err != hipSuccess) {
        // fallback: plain two-kernel path (same math)
        kA<<<dim3(B_ * CIN_), dim3(256), 0, stream>>>(x, X);
        kC<<<dim3(B_ * COUT_), dim3(256), 0, stream>>>(X, wr, wi, out);
    }
}